// Round 1
// baseline (786.832 us; speedup 1.0000x reference)
//
#include <hip/hip_runtime.h>
#include <math.h>

#define S_TOK 2048
#define HID   2048
#define FFN_  2048
#define NEXP  8
#define NSLOT (S_TOK*2)

typedef short  s8v __attribute__((ext_vector_type(8)));
typedef short  s4v __attribute__((ext_vector_type(4)));
typedef float  f4v __attribute__((ext_vector_type(4)));

__device__ __forceinline__ unsigned short f32_bf16(float f){
  unsigned u = __float_as_uint(f);
  u += 0x7fffu + ((u>>16)&1u);          // RNE
  return (unsigned short)(u>>16);
}
// swizzled LDS layout: element (r,k) lives in 8-short granule (r*4 + ((k>>3) ^ ((r>>2)&3)))
// -> b128 fragment reads 2-way (free), granule staging writes ~2-way.
__device__ __forceinline__ int lds_off(int r,int kq){
  return (r*4 + (kq ^ ((r>>2)&3)))*8;
}

// ---------------- init: zero counts/cursors/offs ----------------
__global__ void init_k(int* hdr){
  if (threadIdx.x < 24) hdr[threadIdx.x] = 0;
}

// ---------------- prepass: X fp32 -> bf16 (same layout) ----------------
__global__ __launch_bounds__(256) void convX_k(
    const float* __restrict__ X, unsigned short* __restrict__ Xb)
{
  int i = (blockIdx.x*256 + threadIdx.x)*8;
  f4v a = *reinterpret_cast<const f4v*>(X + i);
  f4v b = *reinterpret_cast<const f4v*>(X + i + 4);
  s8v o;
  o[0]=(short)f32_bf16(a[0]); o[1]=(short)f32_bf16(a[1]);
  o[2]=(short)f32_bf16(a[2]); o[3]=(short)f32_bf16(a[3]);
  o[4]=(short)f32_bf16(b[0]); o[5]=(short)f32_bf16(b[1]);
  o[6]=(short)f32_bf16(b[2]); o[7]=(short)f32_bf16(b[3]);
  *reinterpret_cast<s8v*>(Xb + i) = o;
}

// ---------------- prepass: per-expert [K][N] fp32 -> [N][K] bf16 ----------------
__global__ __launch_bounds__(256) void transp_k(
    const float* __restrict__ src, unsigned short* __restrict__ dst,
    int K, int N)
{
  const int e = blockIdx.z;
  const int n0 = blockIdx.x*64, k0 = blockIdx.y*64;
  src += (size_t)e*K*N;
  dst += (size_t)e*N*K;
  __shared__ __align__(16) unsigned short t[64][72];   // 72 shorts = 144B rows (16B-aligned)
  const int tid = threadIdx.x;
  const int r = tid>>2, cq = tid&3;
  #pragma unroll
  for (int i=0;i<4;i++){
    f4v f = *reinterpret_cast<const f4v*>(src + (size_t)(k0+r)*N + n0 + cq*16 + i*4);
    #pragma unroll
    for (int j=0;j<4;j++) t[cq*16+i*4+j][r] = f32_bf16(f[j]);
  }
  __syncthreads();
  #pragma unroll
  for (int i=0;i<2;i++){
    s8v v = *reinterpret_cast<const s8v*>(&t[r][cq*16 + i*8]);
    *reinterpret_cast<s8v*>(dst + (size_t)(n0+r)*K + k0 + cq*16 + i*8) = v;
  }
}

// ---------------- router: one wave per token, all fp32 ----------------
__global__ __launch_bounds__(64) void router_k(
    const float* __restrict__ X, const float* __restrict__ Wqkv,
    int* __restrict__ hdr, int* __restrict__ idx, float* __restrict__ scr)
{
  const int s = blockIdx.x, lane = threadIdx.x;
  const float* x = X + (size_t)s*HID;
  f4v xv[8];
  #pragma unroll
  for (int i=0;i<8;i++) xv[i] = *reinterpret_cast<const f4v*>(x + (i*64+lane)*4);
  float dot[24];
  #pragma unroll
  for (int o=0;o<24;o++){
    const float* w = Wqkv + (size_t)o*HID;
    float a = 0.f;
    #pragma unroll
    for (int i=0;i<8;i++){
      f4v wv = *reinterpret_cast<const f4v*>(w + (i*64+lane)*4);
      a += xv[i][0]*wv[0] + xv[i][1]*wv[1] + xv[i][2]*wv[2] + xv[i][3]*wv[3];
    }
    #pragma unroll
    for (int off=32; off; off>>=1) a += __shfl_xor(a, off, 64);
    dot[o] = a;
  }
  if (lane==0){
    float lg[8];
    #pragma unroll
    for (int i=0;i<8;i++){
      float qi = dot[i];
      float mx = -1e30f;
      #pragma unroll
      for (int j=0;j<8;j++) mx = fmaxf(mx, qi*dot[8+j]);
      float se=0.f, lv=0.f;
      #pragma unroll
      for (int j=0;j<8;j++){
        float e = expf(qi*dot[8+j] - mx);
        se += e; lv += e*dot[16+j];
      }
      lg[i] = lv/se;
    }
    int i0=0; float v0=lg[0];
    #pragma unroll
    for (int i=1;i<8;i++) if (lg[i]>v0){v0=lg[i];i0=i;}
    int i1=-1; float v1=-1e30f;
    #pragma unroll
    for (int i=0;i<8;i++) if (i!=i0 && lg[i]>v1){v1=lg[i];i1=i;}
    float a  = expf(v1-v0);
    float s0 = 1.f/(1.f+a);
    idx[s*2]=i0; idx[s*2+1]=i1;
    scr[s*2]=s0; scr[s*2+1]=a*s0;
    atomicAdd(&hdr[i0],1); atomicAdd(&hdr[i1],1);
  }
}

// ---------------- scan: exclusive prefix of 8 counts ----------------
__global__ void scan_k(int* hdr){
  if (threadIdx.x==0){
    int a=0;
    for (int e=0;e<NEXP;e++){ hdr[16+e]=a; a+=hdr[e]; }
  }
}

// ---------------- scatter: assign slots ----------------
__global__ __launch_bounds__(256) void scatter_k(
    const int* __restrict__ idx, const float* __restrict__ scr, int* hdr,
    int* __restrict__ slot_of, int* __restrict__ tok_slot, float* __restrict__ scr_slot)
{
  int s = blockIdx.x*256 + threadIdx.x;
  if (s >= S_TOK) return;
  #pragma unroll
  for (int k=0;k<2;k++){
    int e    = idx[s*2+k];
    int pos  = atomicAdd(&hdr[8+e], 1);
    int slot = hdr[16+e] + pos;
    tok_slot[slot] = s;
    scr_slot[slot] = scr[s*2+k];
    slot_of[s*2+k] = slot;
  }
}

// ---------------- grouped GEMM1: inter = silu(X W1g) * (X W1u) ----------------
// grid (FFN/64, S/128, E), block 256. All-bf16 staging, zero in-loop conversion.
__global__ __launch_bounds__(256,2) void gemm1_k(
    const unsigned short* __restrict__ Xb, const unsigned short* __restrict__ W1t,
    const int* __restrict__ hdr, const int* __restrict__ tok_slot,
    unsigned short* __restrict__ inter)
{
  const int e = blockIdx.z, mt = blockIdx.y, nt = blockIdx.x;
  const int cnt = hdr[e];
  const int m0  = mt*128;
  if (m0 >= cnt) return;
  const int off = hdr[16+e];
  const int n0  = nt*64;
  const unsigned short* W1e = W1t + (size_t)e*(2*FFN_)*HID;   // [n' (4096)][k (2048)]

  __shared__ __align__(16) unsigned short sA[128*32];
  __shared__ __align__(16) unsigned short sB[128*32];
  __shared__ int sTok[128];

  const int tid = threadIdx.x;
  if (tid < 128){
    int r = m0 + tid; if (r >= cnt) r = cnt-1;
    sTok[tid] = tok_slot[off + r];
  }
  __syncthreads();

  const int lane = tid & 63, wv = tid >> 6;
  const int wm = wv >> 1, wn = wv & 1;
  const int lm = lane & 15, kq = lane >> 4;
  const int ra = tid >> 2, kg = tid & 3;       // staging: rows ra, ra+64; k-granule kg

  const unsigned short* pA0 = Xb + (size_t)sTok[ra]*HID    + kg*8;
  const unsigned short* pA1 = Xb + (size_t)sTok[ra+64]*HID + kg*8;
  const unsigned short* pB0 = W1e + (size_t)(n0 + ra)*HID        + kg*8;  // gate cols
  const unsigned short* pB1 = W1e + (size_t)(FFN_ + n0 + ra)*HID + kg*8;  // up cols
  unsigned short* qA0 = &sA[lds_off(ra,    kg)];
  unsigned short* qA1 = &sA[lds_off(ra+64, kg)];
  unsigned short* qB0 = &sB[lds_off(ra,    kg)];
  unsigned short* qB1 = &sB[lds_off(ra+64, kg)];

  f4v zero = {0.f,0.f,0.f,0.f};
  f4v acc[2][2][4];
  #pragma unroll
  for (int a=0;a<2;a++)
    #pragma unroll
    for (int b=0;b<2;b++)
      #pragma unroll
      for (int c=0;c<4;c++) acc[a][b][c]=zero;

  s8v a0 = *reinterpret_cast<const s8v*>(pA0);
  s8v a1 = *reinterpret_cast<const s8v*>(pA1);
  s8v b0 = *reinterpret_cast<const s8v*>(pB0);
  s8v b1 = *reinterpret_cast<const s8v*>(pB1);

  for (int k0=0; k0<HID; k0+=32){
    *reinterpret_cast<s8v*>(qA0) = a0;
    *reinterpret_cast<s8v*>(qA1) = a1;
    *reinterpret_cast<s8v*>(qB0) = b0;
    *reinterpret_cast<s8v*>(qB1) = b1;
    __syncthreads();
    if (k0+32 < HID){           // prefetch next tile into regs, hides under MFMA
      a0 = *reinterpret_cast<const s8v*>(pA0 + k0+32);
      a1 = *reinterpret_cast<const s8v*>(pA1 + k0+32);
      b0 = *reinterpret_cast<const s8v*>(pB0 + k0+32);
      b1 = *reinterpret_cast<const s8v*>(pB1 + k0+32);
    }
    s8v af[4], bf_[2][2];
    #pragma unroll
    for (int mf=0;mf<4;mf++)
      af[mf] = *reinterpret_cast<const s8v*>(&sA[lds_off(wm*64+mf*16+lm, kq)]);
    #pragma unroll
    for (int st=0; st<2; st++)
      #pragma unroll
      for (int nf=0;nf<2;nf++)
        bf_[st][nf] = *reinterpret_cast<const s8v*>(&sB[lds_off(st*64+wn*32+nf*16+lm, kq)]);
    #pragma unroll
    for (int st=0; st<2; st++)
      #pragma unroll
      for (int nf=0;nf<2;nf++)
        #pragma unroll
        for (int mf=0;mf<4;mf++)
          acc[st][nf][mf] = __builtin_amdgcn_mfma_f32_16x16x32_bf16(
              af[mf], bf_[st][nf], acc[st][nf][mf], 0,0,0);
    __syncthreads();
  }
  // epilogue: silu(g)*u -> bf16 inter
  const int lq = lane>>4;
  #pragma unroll
  for (int nf=0;nf<2;nf++)
    #pragma unroll
    for (int mf=0;mf<4;mf++){
      f4v g = acc[0][nf][mf], u = acc[1][nf][mf];
      #pragma unroll
      for (int r=0;r<4;r++){
        int row = wm*64 + mf*16 + lq*4 + r;
        if (m0+row < cnt){
          float gv = g[r];
          float val = gv / (1.f + expf(-gv)) * u[r];
          inter[(size_t)(off+m0+row)*FFN_ + n0 + wn*32 + nf*16 + lm] = f32_bf16(val);
        }
      }
    }
}

// ---------------- grouped GEMM2: eout = score * (inter @ W2) ----------------
// grid (HID/128, S/128, E), block 256. All-bf16 staging.
__global__ __launch_bounds__(256,2) void gemm2_k(
    const unsigned short* __restrict__ inter, const unsigned short* __restrict__ W2t,
    const int* __restrict__ hdr, const float* __restrict__ scr_slot,
    float* __restrict__ eout)
{
  const int e = blockIdx.z, mt = blockIdx.y, nt = blockIdx.x;
  const int cnt = hdr[e];
  const int m0  = mt*128;
  if (m0 >= cnt) return;
  const int off = hdr[16+e];
  const int n0  = nt*128;
  const unsigned short* W2e = W2t + (size_t)e*HID*FFN_;      // [n (2048)][k (2048)]

  __shared__ __align__(16) unsigned short sA[128*32];
  __shared__ __align__(16) unsigned short sB[128*32];
  __shared__ float sScr[128];

  const int tid = threadIdx.x;
  if (tid < 128){
    int r = m0 + tid; if (r >= cnt) r = cnt-1;
    sScr[tid] = scr_slot[off + r];
  }

  const int lane = tid & 63, wv = tid >> 6;
  const int wm = wv >> 1, wn = wv & 1;
  const int lm = lane & 15, kq = lane >> 4;
  const int ra = tid >> 2, kg = tid & 3;

  int r0 = m0 + ra;      if (r0 >= cnt) r0 = cnt-1;
  int r1 = m0 + ra + 64; if (r1 >= cnt) r1 = cnt-1;
  const unsigned short* pA0 = inter + (size_t)(off + r0)*FFN_ + kg*8;
  const unsigned short* pA1 = inter + (size_t)(off + r1)*FFN_ + kg*8;
  const unsigned short* pB0 = W2e + (size_t)(n0 + ra)*FFN_      + kg*8;
  const unsigned short* pB1 = W2e + (size_t)(n0 + ra + 64)*FFN_ + kg*8;
  unsigned short* qA0 = &sA[lds_off(ra,    kg)];
  unsigned short* qA1 = &sA[lds_off(ra+64, kg)];
  unsigned short* qB0 = &sB[lds_off(ra,    kg)];
  unsigned short* qB1 = &sB[lds_off(ra+64, kg)];

  f4v zero = {0.f,0.f,0.f,0.f};
  f4v acc[4][4];
  #pragma unroll
  for (int a=0;a<4;a++)
    #pragma unroll
    for (int b=0;b<4;b++) acc[a][b]=zero;

  s8v a0 = *reinterpret_cast<const s8v*>(pA0);
  s8v a1 = *reinterpret_cast<const s8v*>(pA1);
  s8v b0 = *reinterpret_cast<const s8v*>(pB0);
  s8v b1 = *reinterpret_cast<const s8v*>(pB1);

  for (int k0=0; k0<FFN_; k0+=32){
    *reinterpret_cast<s8v*>(qA0) = a0;
    *reinterpret_cast<s8v*>(qA1) = a1;
    *reinterpret_cast<s8v*>(qB0) = b0;
    *reinterpret_cast<s8v*>(qB1) = b1;
    __syncthreads();
    if (k0+32 < FFN_){
      a0 = *reinterpret_cast<const s8v*>(pA0 + k0+32);
      a1 = *reinterpret_cast<const s8v*>(pA1 + k0+32);
      b0 = *reinterpret_cast<const s8v*>(pB0 + k0+32);
      b1 = *reinterpret_cast<const s8v*>(pB1 + k0+32);
    }
    s8v af[4], bf_[4];
    #pragma unroll
    for (int mf=0;mf<4;mf++)
      af[mf] = *reinterpret_cast<const s8v*>(&sA[lds_off(wm*64+mf*16+lm, kq)]);
    #pragma unroll
    for (int nf=0;nf<4;nf++)
      bf_[nf] = *reinterpret_cast<const s8v*>(&sB[lds_off(wn*64+nf*16+lm, kq)]);
    #pragma unroll
    for (int nf=0;nf<4;nf++)
      #pragma unroll
      for (int mf=0;mf<4;mf++)
        acc[nf][mf] = __builtin_amdgcn_mfma_f32_16x16x32_bf16(
            af[mf], bf_[nf], acc[nf][mf], 0,0,0);
    __syncthreads();
  }
  const int lq = lane>>4;
  #pragma unroll
  for (int nf=0;nf<4;nf++)
    #pragma unroll
    for (int mf=0;mf<4;mf++)
      #pragma unroll
      for (int r=0;r<4;r++){
        int row = wm*64 + mf*16 + lq*4 + r;
        if (m0+row < cnt)
          eout[(size_t)(off+m0+row)*HID + n0 + wn*64 + nf*16 + lm] = acc[nf][mf][r]*sScr[row];
      }
}

// ---------------- combine: out[s] = eout[slot0] + eout[slot1] ----------------
__global__ __launch_bounds__(256) void combine_k(
    const float* __restrict__ eout, const int* __restrict__ slot_of,
    float* __restrict__ out)
{
  int s = blockIdx.x, tid = threadIdx.x;
  const float* a = eout + (size_t)slot_of[s*2]  *HID;
  const float* b = eout + (size_t)slot_of[s*2+1]*HID;
  float* o = out + (size_t)s*HID;
  #pragma unroll
  for (int v=tid; v<HID/4; v+=256){
    f4v x = *reinterpret_cast<const f4v*>(a + v*4);
    f4v y = *reinterpret_cast<const f4v*>(b + v*4);
    *reinterpret_cast<f4v*>(o + v*4) = x + y;
  }
}

extern "C" void kernel_launch(void* const* d_in, const int* in_sizes, int n_in,
                              void* d_out, int out_size, void* d_ws, size_t ws_size,
                              hipStream_t stream)
{
  const float* X    = (const float*)d_in[0];
  const float* Wqkv = (const float*)d_in[1];
  const float* W1   = (const float*)d_in[2];
  const float* W2   = (const float*)d_in[3];
  float* out = (float*)d_out;

  // workspace layout (total ~248.1 MB)
  char* ws = (char*)d_ws;
  int*   hdr      = (int*)ws;                              // counts[8], cursor[8], offs[8]
  int*   idx      = (int*)(ws + 4096);
  float* scr      = (float*)(ws + 4096 + 1*16384);
  int*   slot_of  = (int*)(ws + 4096 + 2*16384);
  int*   tok_slot = (int*)(ws + 4096 + 3*16384);
  float* scr_slot = (float*)(ws + 4096 + 4*16384);
  size_t o = 4096 + 5*16384;                               // 86016
  unsigned short* Xb    = (unsigned short*)(ws + o); o += (size_t)S_TOK*HID*2;       // 8 MB
  unsigned short* inter = (unsigned short*)(ws + o); o += (size_t)NSLOT*FFN_*2;      // 16 MB
  float*          eout  = (float*)(ws + o);          o += (size_t)NSLOT*HID*4;       // 32 MB
  unsigned short* W1t   = (unsigned short*)(ws + o); o += (size_t)NEXP*2*FFN_*HID*2; // 128 MB
  unsigned short* W2t   = (unsigned short*)(ws + o);                                 // 64 MB

  init_k   <<<1,   64, 0, stream>>>(hdr);
  // prepass: bf16 conversion + weight transpose (memory-bound, ~600 MB traffic)
  convX_k  <<<(S_TOK*HID/8)/256, 256, 0, stream>>>(X, Xb);
  transp_k <<<dim3((2*FFN_)/64, HID/64, NEXP), 256, 0, stream>>>(W1, W1t, HID, 2*FFN_);
  transp_k <<<dim3(HID/64,     FFN_/64, NEXP), 256, 0, stream>>>(W2, W2t, FFN_, HID);

  router_k <<<S_TOK,64,0, stream>>>(X, Wqkv, hdr, idx, scr);
  scan_k   <<<1,   64, 0, stream>>>(hdr);
  scatter_k<<<(S_TOK+255)/256, 256, 0, stream>>>(idx, scr, hdr, slot_of, tok_slot, scr_slot);
  gemm1_k  <<<dim3(FFN_/64,  S_TOK/128, NEXP), 256, 0, stream>>>(Xb, W1t, hdr, tok_slot, inter);
  gemm2_k  <<<dim3(HID/128,  S_TOK/128, NEXP), 256, 0, stream>>>(inter, W2t, hdr, scr_slot, eout);
  combine_k<<<S_TOK, 256, 0, stream>>>(eout, slot_of, out);
}